// Round 1
// baseline (104.877 us; speedup 1.0000x reference)
//
#include <hip/hip_runtime.h>
#include <cstdint>

// Problem constants (from reference)
#define B 64
#define P 5000
#define G 300
#define C 20
#define SCALE_F 512.0f
#define IOU_TH 0.5f

// Match numpy float32 semantics exactly: no FMA contraction.
#pragma clang fp contract(off)

// ---------------------------------------------------------------------------
// Kernel 1: per-image prep.
//  - stable counting sort of targets by class (preserves original order
//    within a class -> argmax first-occurrence tie-break preserved)
//  - scaled boxes + areas into ws
//  - init firstp[] = INT_MAX
//  - write tcls output
// One block per image.
// ---------------------------------------------------------------------------
__global__ __launch_bounds__(256) void prep_kernel(
    const float* __restrict__ labels,   // [B,G,5]
    float* __restrict__ out_tcls,       // [B,G]
    int* __restrict__ firstp,           // [B,G]
    float* __restrict__ sboxes,         // [B,G,4] scaled, class-sorted
    float* __restrict__ sarea,          // [B,G]
    int* __restrict__ sidx,             // [B,G] original target index
    int* __restrict__ soff)             // [B,C+1] class bucket offsets
{
    const int b = blockIdx.x;
    const int tid = threadIdx.x;
    const float* lab = labels + (size_t)b * G * 5;

    __shared__ int cls_s[G];
    __shared__ int off_s[C + 1];

    for (int t = tid; t < G; t += 256) {
        float c = lab[t * 5 + 4];
        cls_s[t] = (int)c;
        out_tcls[b * G + t] = c;
        firstp[b * G + t] = 0x7FFFFFFF;
    }
    __syncthreads();

    if (tid == 0) {
        int cnt[C];
        for (int c = 0; c < C; ++c) cnt[c] = 0;
        for (int t = 0; t < G; ++t) cnt[cls_s[t]]++;
        int acc = 0;
        for (int c = 0; c < C; ++c) { off_s[c] = acc; acc += cnt[c]; }
        off_s[C] = acc;
    }
    __syncthreads();

    for (int t = tid; t < G; t += 256) {
        int c = cls_s[t];
        int rank = 0;
        for (int u = 0; u < t; ++u) rank += (cls_s[u] == c) ? 1 : 0;
        int pos = b * G + off_s[c] + rank;
        float x1 = lab[t * 5 + 0] * SCALE_F;  // exact (power of two)
        float y1 = lab[t * 5 + 1] * SCALE_F;
        float x2 = lab[t * 5 + 2] * SCALE_F;
        float y2 = lab[t * 5 + 3] * SCALE_F;
        sboxes[pos * 4 + 0] = x1;
        sboxes[pos * 4 + 1] = y1;
        sboxes[pos * 4 + 2] = x2;
        sboxes[pos * 4 + 3] = y2;
        sarea[pos] = (x2 - x1) * (y2 - y1);
        sidx[pos] = t;
    }
    if (tid <= C) soff[b * (C + 1) + tid] = off_s[tid];
}

// ---------------------------------------------------------------------------
// Kernel 2: per-prediction match. One thread per (b,p); targets for image b
// staged in LDS. Loops only this prediction's class bucket.
// ---------------------------------------------------------------------------
__global__ __launch_bounds__(256) void match_kernel(
    const float* __restrict__ preds,    // [B,P,6]
    const float* __restrict__ sboxes,
    const float* __restrict__ sarea,
    const int* __restrict__ sidx,
    const int* __restrict__ soff,
    int* __restrict__ firstp,           // [B,G] atomicMin target
    int* __restrict__ bestidx,          // [B,P] bi if eligible else -1
    float* __restrict__ out_stats)      // [B,P,3]
{
    const int b = blockIdx.y;
    const int tid = threadIdx.x;

    __shared__ float sb[G * 4];
    __shared__ float sa[G];
    __shared__ int si[G];
    __shared__ int so[C + 1];

    for (int i = tid; i < G * 4; i += 256) sb[i] = sboxes[(size_t)b * G * 4 + i];
    for (int i = tid; i < G; i += 256) {
        sa[i] = sarea[b * G + i];
        si[i] = sidx[b * G + i];
    }
    if (tid <= C) so[tid] = soff[b * (C + 1) + tid];
    __syncthreads();

    const int p = blockIdx.x * 256 + tid;
    if (p >= P) return;

    const float* pr = preds + ((size_t)b * P + p) * 6;
    float px1 = pr[0] * SCALE_F;
    float py1 = pr[1] * SCALE_F;
    float px2 = pr[2] * SCALE_F;
    float py2 = pr[3] * SCALE_F;
    float score = pr[4];
    float fcls = pr[5];
    int c = (int)fcls;
    float parea = (px2 - px1) * (py2 - py1);

    int lo = so[c], hi = so[c + 1];
    float best = -1.0f;
    int bi = -1;
    // Bucket is in original-index order; strict > keeps the FIRST occurrence
    // of the max, matching jnp.argmax tie-break.
    for (int j = lo; j < hi; ++j) {
        float lx = fmaxf(px1, sb[j * 4 + 0]);
        float ly = fmaxf(py1, sb[j * 4 + 1]);
        float rx = fminf(px2, sb[j * 4 + 2]);
        float ry = fminf(py2, sb[j * 4 + 3]);
        float w = fmaxf(rx - lx, 0.0f);
        float h = fmaxf(ry - ly, 0.0f);
        float inter = w * h;
        float uni = (parea + sa[j]) - inter;   // same assoc order as reference
        float iou = inter / uni;               // IEEE div (no fast-math)
        if (iou > best) { best = iou; bi = si[j]; }
    }

    bool eligible = (score > 0.0f) && (hi > lo) && (best > IOU_TH);
    size_t op = (size_t)b * P + p;
    bestidx[op] = eligible ? bi : -1;
    if (eligible) atomicMin(&firstp[b * G + bi], p);
    out_stats[op * 3 + 1] = score;
    out_stats[op * 3 + 2] = fcls;
}

// ---------------------------------------------------------------------------
// Kernel 3: finalize. First eligible prediction (lowest p) claiming a target
// gets correct=1; everyone else 0.
// ---------------------------------------------------------------------------
__global__ __launch_bounds__(256) void final_kernel(
    const int* __restrict__ firstp,
    const int* __restrict__ bestidx,
    float* __restrict__ out_stats)
{
    int i = blockIdx.x * 256 + threadIdx.x;   // over B*P
    if (i >= B * P) return;
    int b = i / P;
    int p = i - b * P;
    int bi = bestidx[i];
    float corr = 0.0f;
    if (bi >= 0 && firstp[b * G + bi] == p) corr = 1.0f;
    out_stats[(size_t)i * 3 + 0] = corr;
}

extern "C" void kernel_launch(void* const* d_in, const int* in_sizes, int n_in,
                              void* d_out, int out_size, void* d_ws, size_t ws_size,
                              hipStream_t stream) {
    const float* output = (const float*)d_in[0];   // [B,P,6]
    const float* labels = (const float*)d_in[1];   // [B,G,5]

    float* out_stats = (float*)d_out;                       // [B,P,3]
    float* out_tcls  = (float*)d_out + (size_t)B * P * 3;   // [B,G]

    // workspace layout (all 4-byte elements)
    int* firstp  = (int*)d_ws;                 // B*G
    int* bestidx = firstp + B * G;             // B*P
    int* sidx    = bestidx + (size_t)B * P;    // B*G
    int* soff    = sidx + B * G;               // B*(C+1)
    float* sboxes = (float*)(soff + B * (C + 1)); // B*G*4
    float* sarea  = sboxes + (size_t)B * G * 4;   // B*G

    prep_kernel<<<B, 256, 0, stream>>>(labels, out_tcls, firstp, sboxes, sarea, sidx, soff);

    dim3 g2((P + 255) / 256, B);
    match_kernel<<<g2, 256, 0, stream>>>(output, sboxes, sarea, sidx, soff,
                                         firstp, bestidx, out_stats);

    final_kernel<<<(B * P + 255) / 256, 256, 0, stream>>>(firstp, bestidx, out_stats);
}

// Round 2
// 92.970 us; speedup vs baseline: 1.1281x; 1.1281x over previous
//
#include <hip/hip_runtime.h>
#include <cstdint>

// Problem constants (from reference)
#define B 64
#define P 5000
#define G 300
#define C 20
#define SCALE_F 512.0f
#define IOU_TH 0.5f
#define NT 1024              // threads per block
#define PPT ((P + NT - 1) / NT)   // predictions per thread = 5

// Match numpy float32 semantics exactly: no FMA contraction (hipcc defaults
// to contract=fast). Division stays IEEE (no -ffast-math).
#pragma clang fp contract(off)

// ---------------------------------------------------------------------------
// One block per image. Everything in LDS:
//  1. stable counting sort of targets by class (original order preserved
//     within a class -> jnp.argmax first-occurrence tie-break preserved)
//  2. per-prediction match against its class bucket, claim via LDS atomicMin
//  3. resolve: first (lowest p) eligible claimant of each target wins
// Key identity: the reference's argmax does not depend on `detected`, so the
// sequential scan collapses to "first eligible claimant per target".
// ---------------------------------------------------------------------------
__global__ __launch_bounds__(NT) void fused_kernel(
    const float* __restrict__ preds,    // [B,P,6]
    const float* __restrict__ labels,   // [B,G,5]
    float* __restrict__ out_stats,      // [B,P,3]
    float* __restrict__ out_tcls)       // [B,G]
{
    const int b = blockIdx.x;
    const int tid = threadIdx.x;

    __shared__ float4 sb[G];      // class-sorted scaled boxes
    __shared__ float  sa[G];      // class-sorted areas
    __shared__ int    ssi[G];     // sorted pos -> original target idx
    __shared__ int    so[C + 1];  // class bucket offsets
    __shared__ int    cls_s[G];
    __shared__ int    firstp[G];  // lowest eligible p claiming each target
    __shared__ int    cnt[C];

    const float* lab = labels + (size_t)b * G * 5;

    if (tid < C) cnt[tid] = 0;
    for (int t = tid; t < G; t += NT) {
        float c = lab[t * 5 + 4];
        cls_s[t] = (int)c;
        out_tcls[b * G + t] = c;
        firstp[t] = 0x7FFFFFFF;
    }
    __syncthreads();

    for (int t = tid; t < G; t += NT) atomicAdd(&cnt[cls_s[t]], 1);
    __syncthreads();

    if (tid == 0) {
        int acc = 0;
        for (int c = 0; c < C; ++c) { so[c] = acc; acc += cnt[c]; }
        so[C] = acc;
    }
    __syncthreads();

    // stable rank + scatter (G=300 < NT: each thread handles <=1 target)
    for (int t = tid; t < G; t += NT) {
        int c = cls_s[t];
        int rank = 0;
        for (int u = 0; u < t; ++u) rank += (cls_s[u] == c) ? 1 : 0;
        int pos = so[c] + rank;
        float x1 = lab[t * 5 + 0] * SCALE_F;   // *512 is exact (pow2)
        float y1 = lab[t * 5 + 1] * SCALE_F;
        float x2 = lab[t * 5 + 2] * SCALE_F;
        float y2 = lab[t * 5 + 3] * SCALE_F;
        sb[pos] = make_float4(x1, y1, x2, y2);
        sa[pos] = (x2 - x1) * (y2 - y1);
        ssi[pos] = t;
    }
    __syncthreads();

    // ---- match phase: each thread owns preds p = tid + k*NT ----
    int mybi[PPT];
    #pragma unroll
    for (int k = 0; k < PPT; ++k) {
        int p = tid + k * NT;
        mybi[k] = -1;
        if (p >= P) continue;
        const float* pr = preds + ((size_t)b * P + p) * 6;
        float px1 = pr[0] * SCALE_F;
        float py1 = pr[1] * SCALE_F;
        float px2 = pr[2] * SCALE_F;
        float py2 = pr[3] * SCALE_F;
        float score = pr[4];
        float fcls = pr[5];
        int c = (int)fcls;
        float parea = (px2 - px1) * (py2 - py1);

        int lo = so[c], hi = so[c + 1];
        float best = -1.0f;
        int bi = -1;
        // bucket preserves original order; strict > keeps FIRST max occurrence
        for (int j = lo; j < hi; ++j) {
            float4 tb = sb[j];
            float lx = fmaxf(px1, tb.x);
            float ly = fmaxf(py1, tb.y);
            float rx = fminf(px2, tb.z);
            float ry = fminf(py2, tb.w);
            float w = fmaxf(rx - lx, 0.0f);
            float h = fmaxf(ry - ly, 0.0f);
            float inter = w * h;
            float uni = (parea + sa[j]) - inter;   // reference assoc order
            float iou = inter / uni;               // IEEE div
            if (iou > best) { best = iou; bi = ssi[j]; }
        }

        bool eligible = (score > 0.0f) && (hi > lo) && (best > IOU_TH);
        if (eligible) {
            mybi[k] = bi;
            atomicMin(&firstp[bi], p);
        }
        size_t op = (size_t)b * P + p;
        out_stats[op * 3 + 1] = score;
        out_stats[op * 3 + 2] = fcls;
    }
    __syncthreads();

    // ---- resolve phase ----
    #pragma unroll
    for (int k = 0; k < PPT; ++k) {
        int p = tid + k * NT;
        if (p >= P) continue;
        int bi = mybi[k];
        float corr = (bi >= 0 && firstp[bi] == p) ? 1.0f : 0.0f;
        out_stats[((size_t)b * P + p) * 3 + 0] = corr;
    }
}

extern "C" void kernel_launch(void* const* d_in, const int* in_sizes, int n_in,
                              void* d_out, int out_size, void* d_ws, size_t ws_size,
                              hipStream_t stream) {
    const float* output = (const float*)d_in[0];   // [B,P,6]
    const float* labels = (const float*)d_in[1];   // [B,G,5]

    float* out_stats = (float*)d_out;                       // [B,P,3]
    float* out_tcls  = (float*)d_out + (size_t)B * P * 3;   // [B,G]

    fused_kernel<<<B, NT, 0, stream>>>(output, labels, out_stats, out_tcls);
}